// Round 1
// baseline (389.568 us; speedup 1.0000x reference)
//
#include <hip/hip_runtime.h>

typedef unsigned long long ull;

#define NB    16      // batches
#define NPTS  65536   // points per batch
#define NSEED 40      // seeds
#define BPB   16      // blocks per batch
#define TPB   1024    // threads per block
#define PPT   4       // points per thread = NPTS/(BPB*TPB)
#define R2    0.0025f // RADIUS^2

// pack (value, index) so that unsigned max == (max value, then smallest index)
__device__ __forceinline__ ull packdi(float v, int idx) {
  return ((ull)__float_as_uint(v) << 16) | (ull)((unsigned)(idx ^ 0xFFFF) & 0xFFFFu);
}

__global__ __launch_bounds__(TPB, 4) void fps_den_kernel(
    const float* __restrict__ pcs, ull* __restrict__ slots, float* __restrict__ den)
{
  const int beta = blockIdx.x >> 4;   // batch
  const int blk  = blockIdx.x & 15;   // block within batch
  const int tid  = threadIdx.x;
  const float* __restrict__ base = pcs + (size_t)beta * (NPTS * 3);

  __shared__ float sC[3];
  __shared__ ull   sRed[TPB / 64];
  __shared__ float sSx[NSEED], sSy[NSEED], sSz[NSEED];

  // register-resident points + running min-distance
  float px[PPT], py[PPT], pz[PPT], dist[PPT];
  int   nidx[PPT];
#pragma unroll
  for (int j = 0; j < PPT; ++j) {
    int n   = blk * (TPB * PPT) + j * TPB + tid;
    nidx[j] = n;
    px[j]   = base[n * 3 + 0];
    py[j]   = base[n * 3 + 1];
    pz[j]   = base[n * 3 + 2];
    dist[j] = 1e10f;
  }

  if (tid == 0) {
    float cx = base[0], cy = base[1], cz = base[2];   // seed 0 is point 0
    sC[0] = cx; sC[1] = cy; sC[2] = cz;
    sSx[0] = cx; sSy[0] = cy; sSz[0] = cz;
  }
  __syncthreads();

  ull* myslots = slots + (size_t)beta * 2 * BPB;   // parity double-buffered

  for (int k = 0; k < NSEED - 1; ++k) {
    float cx = sC[0], cy = sC[1], cz = sC[2];
    ull best = 0;
#pragma unroll
    for (int j = 0; j < PPT; ++j) {
      float dx = px[j] - cx, dy = py[j] - cy, dz = pz[j] - cz;
      // match numpy: round each square, sum as (d0+d1)+d2, no FMA contraction
      float d  = __fadd_rn(__fadd_rn(__fmul_rn(dx, dx), __fmul_rn(dy, dy)),
                           __fmul_rn(dz, dz));
      float nd = fminf(dist[j], d);
      dist[j]  = nd;
      ull p    = packdi(nd, nidx[j]);
      best     = best > p ? best : p;
    }
    // wave-level argmax
#pragma unroll
    for (int o = 32; o > 0; o >>= 1) {
      ull q = __shfl_xor(best, o, 64);
      best  = best > q ? best : q;
    }
    if ((tid & 63) == 0) sRed[tid >> 6] = best;
    __syncthreads();

    if (tid == 0) {
      ull m = sRed[0];
#pragma unroll
      for (int i = 1; i < TPB / 64; ++i) m = m > sRed[i] ? m : sRed[i];
      const ull gen = (ull)(k + 1);
      ull* arr = myslots + ((k + 1) & 1) * BPB;
      __hip_atomic_store(&arr[blk], (gen << 48) | (m & 0xFFFFFFFFFFFFull),
                         __ATOMIC_RELEASE, __HIP_MEMORY_SCOPE_AGENT);
      // poll sibling blocks (gen-tagged; parity buffer prevents clobber races)
      ull win = 0;
      for (;;) {
        bool ok = true; ull mm = 0;
        for (int i = 0; i < BPB; ++i) {
          ull v = __hip_atomic_load(&arr[i], __ATOMIC_RELAXED,
                                    __HIP_MEMORY_SCOPE_AGENT);
          if ((v >> 48) != gen) { ok = false; break; }
          mm = mm > v ? mm : v;
        }
        if (ok) { win = mm; break; }
        __builtin_amdgcn_s_sleep(2);
      }
      int widx = 0xFFFF ^ (int)(win & 0xFFFFull);
      float nx = base[widx * 3 + 0], ny = base[widx * 3 + 1], nz = base[widx * 3 + 2];
      sC[0] = nx; sC[1] = ny; sC[2] = nz;
      sSx[k + 1] = nx; sSy[k + 1] = ny; sSz[k + 1] = nz;
    }
    __syncthreads();
  }

  // ---- density phase: points already in registers, seeds in LDS ----
  float* dden = den + beta * NSEED;
  for (int s = 0; s < NSEED; ++s) {
    float sx = sSx[s], sy = sSy[s], sz = sSz[s];
    float a = 0.f;
#pragma unroll
    for (int j = 0; j < PPT; ++j) {
      float dx = px[j] - sx, dy = py[j] - sy, dz = pz[j] - sz;
      float d  = dx * dx + dy * dy + dz * dz;
      a += fmaxf(R2 - d, 0.f);
    }
#pragma unroll
    for (int o = 32; o > 0; o >>= 1) a += __shfl_xor(a, o, 64);
    if ((tid & 63) == 0) atomicAdd(&dden[s], a);
  }
}

__global__ void var_kernel(const float* __restrict__ den, float* __restrict__ out) {
  int l = threadIdx.x;
  float v = 0.f;
  if (l < NB) {
    float m = 0.f;
    for (int s = 0; s < NSEED; ++s) m += den[l * NSEED + s];
    m /= (float)NSEED;
    float q = 0.f;
    for (int s = 0; s < NSEED; ++s) { float d = den[l * NSEED + s] - m; q += d * d; }
    v = q / (float)(NSEED - 1);   // ddof=1
  }
  for (int o = 32; o > 0; o >>= 1) v += __shfl_xor(v, o, 64);
  if (l == 0) out[0] = v / (float)NB;
}

extern "C" void kernel_launch(void* const* d_in, const int* in_sizes, int n_in,
                              void* d_out, int out_size, void* d_ws, size_t ws_size,
                              hipStream_t stream) {
  const float* pcs = (const float*)d_in[0];
  float* out  = (float*)d_out;
  float* den  = (float*)d_ws;                       // 16*40*4   = 2560 B
  ull*   slots = (ull*)((char*)d_ws + 2560);        // 16*2*16*8 = 4096 B

  hipMemsetAsync(den, 0, NB * NSEED * sizeof(float), stream);

  void* args[3];
  args[0] = (void*)&pcs;
  args[1] = (void*)&slots;
  args[2] = (void*)&den;
  hipLaunchCooperativeKernel(reinterpret_cast<void*>(fps_den_kernel),
                             dim3(NB * BPB), dim3(TPB), args, 0, stream);

  hipLaunchKernelGGL(var_kernel, dim3(1), dim3(64), 0, stream, den, out);
}

// Round 2
// 364.998 us; speedup vs baseline: 1.0673x; 1.0673x over previous
//
#include <hip/hip_runtime.h>

typedef unsigned long long ull;

#define NB    16      // batches
#define NPTS  65536   // points per batch
#define NSEED 40      // seeds
#define BPB   16      // blocks per batch
#define TPB   1024    // threads per block (16 waves)
#define NW    (TPB/64)
#define PPT   4       // points per thread = NPTS/(BPB*TPB)
#define R2    0.0025f // RADIUS^2
#define PAYLOAD 0xFFFFFFFFFFFFull

// pack (value, index): unsigned max == (max value, then smallest index)
__device__ __forceinline__ ull packdi(float v, int idx) {
  return ((ull)__float_as_uint(v) << 16) | (ull)((unsigned)(idx ^ 0xFFFF) & 0xFFFFu);
}

__global__ __launch_bounds__(TPB, 4) void fps_den_kernel(
    const float* __restrict__ pcs, ull* __restrict__ slots, float* __restrict__ den)
{
  const int beta = blockIdx.x >> 4;   // batch
  const int blk  = blockIdx.x & 15;   // block within batch
  const int tid  = threadIdx.x;
  const int lane = tid & 63;
  const float* __restrict__ base = pcs + (size_t)beta * (NPTS * 3);

  __shared__ ull   sRed[2][NW];       // parity double-buffered (1-barrier/round scheme)
  __shared__ float sSx[NSEED], sSy[NSEED], sSz[NSEED];

  // register-resident points + running min-distance
  float px[PPT], py[PPT], pz[PPT], dist[PPT];
#pragma unroll
  for (int j = 0; j < PPT; ++j) {
    int n = blk * (TPB * PPT) + j * TPB + tid;
    px[j] = base[n * 3 + 0];
    py[j] = base[n * 3 + 1];
    pz[j] = base[n * 3 + 2];
    dist[j] = 1e10f;
  }

  float cx = base[0], cy = base[1], cz = base[2];   // seed 0 = point 0
  if (tid == 0) { sSx[0] = cx; sSy[0] = cy; sSz[0] = cz; }

  ull* myslots = slots + (size_t)beta * 2 * BPB;    // parity double-buffered

  for (int k = 0; k < NSEED - 1; ++k) {
    ull best = 0;
#pragma unroll
    for (int j = 0; j < PPT; ++j) {
      float dx = px[j] - cx, dy = py[j] - cy, dz = pz[j] - cz;
      // match numpy: round each square, sum as (d0+d1)+d2, no FMA contraction
      float d  = __fadd_rn(__fadd_rn(__fmul_rn(dx, dx), __fmul_rn(dy, dy)),
                           __fmul_rn(dz, dz));
      float nd = fminf(dist[j], d);
      dist[j]  = nd;
      int n    = blk * (TPB * PPT) + j * TPB + tid;
      ull p    = packdi(nd, n);
      best     = best > p ? best : p;
    }
    // wave-level argmax (butterfly)
#pragma unroll
    for (int o = 32; o > 0; o >>= 1) {
      ull q = __shfl_xor(best, o, 64);
      best  = best > q ? best : q;
    }
    if (lane == 0) sRed[k & 1][tid >> 6] = best;
    __syncthreads();   // the ONLY barrier in the round

    // every wave: cross-wave max via lanes 0..NW-1 (lane-parallel)
    ull r = (lane < NW) ? sRed[k & 1][lane] : 0;
#pragma unroll
    for (int o = 8; o > 0; o >>= 1) {
      ull q = __shfl_xor(r, o, 64);
      r = r > q ? r : q;
    }
    ull blockbest = __shfl(r, 0, 64);

    const ull gen = (ull)(k + 1);
    ull* arr = myslots + ((k + 1) & 1) * BPB;
    if (tid == 0)
      __hip_atomic_store(&arr[blk], (gen << 48) | (blockbest & PAYLOAD),
                         __ATOMIC_RELEASE, __HIP_MEMORY_SCOPE_AGENT);

    // every wave polls: lanes 0..15 each watch one sibling slot in parallel
    ull win;
    for (;;) {
      ull v = 0;
      if (lane < BPB)
        v = __hip_atomic_load(&arr[lane], __ATOMIC_RELAXED,
                              __HIP_MEMORY_SCOPE_AGENT);
      int ok = (lane < BPB) ? (int)((v >> 48) == gen) : 1;
      if (__all(ok)) {
        ull w2 = (lane < BPB) ? (v & PAYLOAD) : 0;
#pragma unroll
        for (int o = 8; o > 0; o >>= 1) {
          ull q = __shfl_xor(w2, o, 64);
          w2 = w2 > q ? w2 : q;
        }
        win = __shfl(w2, 0, 64);
        break;
      }
      __builtin_amdgcn_s_sleep(1);
    }

    int widx = 0xFFFF ^ (int)(win & 0xFFFFull);
    // same-address broadcast load; pcs is read-only so L1 is safe
    cx = base[widx * 3 + 0];
    cy = base[widx * 3 + 1];
    cz = base[widx * 3 + 2];
    if (tid == 0) { sSx[k + 1] = cx; sSy[k + 1] = cy; sSz[k + 1] = cz; }
  }
  __syncthreads();   // sS[] complete before density phase

  // ---- density phase: points already in registers, seeds in LDS ----
  float* dden = den + beta * NSEED;
  for (int s = 0; s < NSEED; ++s) {
    float sx = sSx[s], sy = sSy[s], sz = sSz[s];
    float a = 0.f;
#pragma unroll
    for (int j = 0; j < PPT; ++j) {
      float dx = px[j] - sx, dy = py[j] - sy, dz = pz[j] - sz;
      float d  = dx * dx + dy * dy + dz * dz;
      a += fmaxf(R2 - d, 0.f);
    }
#pragma unroll
    for (int o = 32; o > 0; o >>= 1) a += __shfl_xor(a, o, 64);
    if (lane == 0) atomicAdd(&dden[s], a);
  }
}

__global__ void var_kernel(const float* __restrict__ den, float* __restrict__ out) {
  int l = threadIdx.x;
  float v = 0.f;
  if (l < NB) {
    float m = 0.f;
    for (int s = 0; s < NSEED; ++s) m += den[l * NSEED + s];
    m /= (float)NSEED;
    float q = 0.f;
    for (int s = 0; s < NSEED; ++s) { float d = den[l * NSEED + s] - m; q += d * d; }
    v = q / (float)(NSEED - 1);   // ddof=1
  }
  for (int o = 32; o > 0; o >>= 1) v += __shfl_xor(v, o, 64);
  if (l == 0) out[0] = v / (float)NB;
}

extern "C" void kernel_launch(void* const* d_in, const int* in_sizes, int n_in,
                              void* d_out, int out_size, void* d_ws, size_t ws_size,
                              hipStream_t stream) {
  const float* pcs = (const float*)d_in[0];
  float* out  = (float*)d_out;
  float* den  = (float*)d_ws;                       // 16*40*4   = 2560 B
  ull*   slots = (ull*)((char*)d_ws + 2560);        // 16*2*16*8 = 4096 B
  // slots need no init: poisoned 0xAA.. gives gen tag 0xAAAA, never in 1..39

  hipMemsetAsync(den, 0, NB * NSEED * sizeof(float), stream);

  void* args[3];
  args[0] = (void*)&pcs;
  args[1] = (void*)&slots;
  args[2] = (void*)&den;
  hipLaunchCooperativeKernel(reinterpret_cast<void*>(fps_den_kernel),
                             dim3(NB * BPB), dim3(TPB), args, 0, stream);

  hipLaunchKernelGGL(var_kernel, dim3(1), dim3(64), 0, stream, den, out);
}

// Round 3
// 341.259 us; speedup vs baseline: 1.1416x; 1.0696x over previous
//
#include <hip/hip_runtime.h>

typedef unsigned long long ull;

#define NB    16      // batches
#define NPTS  65536   // points per batch
#define NSEED 40      // seeds
#define BPB   16      // blocks per batch
#define TPB   1024    // threads per block (16 waves)
#define NW    (TPB/64)
#define PPT   4       // points per thread = NPTS/(BPB*TPB)
#define R2    0.0025f // RADIUS^2
#define PAYLOAD 0xFFFFFFFFFFFFull

// pack (value, index): unsigned max == (max value, then smallest index)
__device__ __forceinline__ ull packdi(float v, int idx) {
  return ((ull)__float_as_uint(v) << 16) | (ull)((unsigned)(idx ^ 0xFFFF) & 0xFFFFu);
}

__global__ __launch_bounds__(TPB, 4) void fps_den_kernel(
    const float* __restrict__ pcs, ull* __restrict__ slots, float* __restrict__ den)
{
  const int beta = blockIdx.x >> 4;   // batch
  const int blk  = blockIdx.x & 15;   // block within batch
  const int tid  = threadIdx.x;
  const int lane = tid & 63;
  const float* __restrict__ base = pcs + (size_t)beta * (NPTS * 3);

  __shared__ ull   sRed[2][NW];       // parity double-buffered (1-barrier/round scheme)
  __shared__ float sSx[NSEED], sSy[NSEED], sSz[NSEED];

  // register-resident points + running min-distance
  float px[PPT], py[PPT], pz[PPT], dist[PPT];
#pragma unroll
  for (int j = 0; j < PPT; ++j) {
    int n = blk * (TPB * PPT) + j * TPB + tid;
    px[j] = base[n * 3 + 0];
    py[j] = base[n * 3 + 1];
    pz[j] = base[n * 3 + 2];
    dist[j] = 1e10f;
  }

  float cx = base[0], cy = base[1], cz = base[2];   // seed 0 = point 0
  if (tid == 0) { sSx[0] = cx; sSy[0] = cy; sSz[0] = cz; }

  ull* myslots = slots + (size_t)beta * 2 * BPB;    // parity double-buffered

  for (int k = 0; k < NSEED - 1; ++k) {
    ull best = 0;
#pragma unroll
    for (int j = 0; j < PPT; ++j) {
      float dx = px[j] - cx, dy = py[j] - cy, dz = pz[j] - cz;
      // match numpy: round each square, sum as (d0+d1)+d2, no FMA contraction
      float d  = __fadd_rn(__fadd_rn(__fmul_rn(dx, dx), __fmul_rn(dy, dy)),
                           __fmul_rn(dz, dz));
      float nd = fminf(dist[j], d);
      dist[j]  = nd;
      int n    = blk * (TPB * PPT) + j * TPB + tid;
      ull p    = packdi(nd, n);
      best     = best > p ? best : p;
    }
    // wave-level argmax (butterfly)
#pragma unroll
    for (int o = 32; o > 0; o >>= 1) {
      ull q = __shfl_xor(best, o, 64);
      best  = best > q ? best : q;
    }
    if (lane == 0) sRed[k & 1][tid >> 6] = best;
    __syncthreads();   // the ONLY barrier in the round

    // every wave: cross-wave max via lanes 0..NW-1 (lane-parallel)
    ull r = (lane < NW) ? sRed[k & 1][lane] : 0;
#pragma unroll
    for (int o = 8; o > 0; o >>= 1) {
      ull q = __shfl_xor(r, o, 64);
      r = r > q ? r : q;
    }
    ull blockbest = __shfl(r, 0, 64);

    const ull gen = (ull)(k + 1);
    ull* arr = myslots + ((k + 1) & 1) * BPB;
    // RELAXED is sufficient: gen tag + payload are ONE atomic 64-bit word;
    // no other memory is communicated cross-block. RELEASE at agent scope
    // emits buffer_wbl2 (full L2 writeback) on multi-XCD gfx950 — ~8us/round.
    if (tid == 0)
      __hip_atomic_store(&arr[blk], (gen << 48) | (blockbest & PAYLOAD),
                         __ATOMIC_RELAXED, __HIP_MEMORY_SCOPE_AGENT);

    // every wave polls: lanes 0..15 each watch one sibling slot in parallel
    ull win;
    for (;;) {
      ull v = 0;
      if (lane < BPB)
        v = __hip_atomic_load(&arr[lane], __ATOMIC_RELAXED,
                              __HIP_MEMORY_SCOPE_AGENT);
      int ok = (lane < BPB) ? (int)((v >> 48) == gen) : 1;
      if (__all(ok)) {
        ull w2 = (lane < BPB) ? (v & PAYLOAD) : 0;
#pragma unroll
        for (int o = 8; o > 0; o >>= 1) {
          ull q = __shfl_xor(w2, o, 64);
          w2 = w2 > q ? w2 : q;
        }
        win = __shfl(w2, 0, 64);
        break;
      }
      __builtin_amdgcn_s_sleep(1);
    }

    int widx = 0xFFFF ^ (int)(win & 0xFFFFull);
    // same-address broadcast load; pcs is read-only so L1 is safe
    cx = base[widx * 3 + 0];
    cy = base[widx * 3 + 1];
    cz = base[widx * 3 + 2];
    if (tid == 0) { sSx[k + 1] = cx; sSy[k + 1] = cy; sSz[k + 1] = cz; }
  }
  __syncthreads();   // sS[] complete before density phase

  // ---- density phase: points already in registers, seeds in LDS ----
  float* dden = den + beta * NSEED;
  for (int s = 0; s < NSEED; ++s) {
    float sx = sSx[s], sy = sSy[s], sz = sSz[s];
    float a = 0.f;
#pragma unroll
    for (int j = 0; j < PPT; ++j) {
      float dx = px[j] - sx, dy = py[j] - sy, dz = pz[j] - sz;
      float d  = dx * dx + dy * dy + dz * dz;
      a += fmaxf(R2 - d, 0.f);
    }
#pragma unroll
    for (int o = 32; o > 0; o >>= 1) a += __shfl_xor(a, o, 64);
    if (lane == 0) atomicAdd(&dden[s], a);
  }
}

__global__ void var_kernel(const float* __restrict__ den, float* __restrict__ out) {
  int l = threadIdx.x;
  float v = 0.f;
  if (l < NB) {
    float m = 0.f;
    for (int s = 0; s < NSEED; ++s) m += den[l * NSEED + s];
    m /= (float)NSEED;
    float q = 0.f;
    for (int s = 0; s < NSEED; ++s) { float d = den[l * NSEED + s] - m; q += d * d; }
    v = q / (float)(NSEED - 1);   // ddof=1
  }
  for (int o = 32; o > 0; o >>= 1) v += __shfl_xor(v, o, 64);
  if (l == 0) out[0] = v / (float)NB;
}

extern "C" void kernel_launch(void* const* d_in, const int* in_sizes, int n_in,
                              void* d_out, int out_size, void* d_ws, size_t ws_size,
                              hipStream_t stream) {
  const float* pcs = (const float*)d_in[0];
  float* out  = (float*)d_out;
  float* den  = (float*)d_ws;                       // 16*40*4   = 2560 B
  ull*   slots = (ull*)((char*)d_ws + 2560);        // 16*2*16*8 = 4096 B
  // slots need no init: poisoned 0xAA.. gives gen tag 0xAAAA, never in 1..39

  hipMemsetAsync(den, 0, NB * NSEED * sizeof(float), stream);

  void* args[3];
  args[0] = (void*)&pcs;
  args[1] = (void*)&slots;
  args[2] = (void*)&den;
  hipLaunchCooperativeKernel(reinterpret_cast<void*>(fps_den_kernel),
                             dim3(NB * BPB), dim3(TPB), args, 0, stream);

  hipLaunchKernelGGL(var_kernel, dim3(1), dim3(64), 0, stream, den, out);
}

// Round 4
// 286.725 us; speedup vs baseline: 1.3587x; 1.1902x over previous
//
#include <hip/hip_runtime.h>

typedef unsigned long long ull;

#define NB    16      // batches
#define NPTS  65536   // points per batch
#define NSEED 40      // seeds
#define BPB   16      // blocks per batch
#define TPB   1024    // threads per block (16 waves)
#define NW    (TPB/64)
#define PPT   4       // points per thread = NPTS/(BPB*TPB)
#define R2    0.0025f // RADIUS^2
#define PAYLOAD 0xFFFFFFFFFFFFull

// pack (value, index): unsigned max == (max value, then smallest index)
__device__ __forceinline__ ull packdi(float v, int idx) {
  return ((ull)__float_as_uint(v) << 16) | (ull)((unsigned)(idx ^ 0xFFFF) & 0xFFFFu);
}

__global__ __launch_bounds__(TPB, 4) void fps_den_kernel(
    const float* __restrict__ pcs, ull* __restrict__ slots, float* __restrict__ den)
{
  const int beta = blockIdx.x >> 4;   // batch
  const int blk  = blockIdx.x & 15;   // block within batch
  const int tid  = threadIdx.x;
  const int lane = tid & 63;
  const float* __restrict__ base = pcs + (size_t)beta * (NPTS * 3);

  __shared__ ull   sRed[2][NW];   // parity double-buffered wave maxima
  __shared__ ull   sWin[2];       // parity double-buffered round winner
  __shared__ float sSx[NSEED], sSy[NSEED], sSz[NSEED];

  // register-resident points + running min-distance
  float px[PPT], py[PPT], pz[PPT], dist[PPT];
#pragma unroll
  for (int j = 0; j < PPT; ++j) {
    int n = blk * (TPB * PPT) + j * TPB + tid;
    px[j] = base[n * 3 + 0];
    py[j] = base[n * 3 + 1];
    pz[j] = base[n * 3 + 2];
    dist[j] = 1e10f;
  }

  float cx = base[0], cy = base[1], cz = base[2];   // seed 0 = point 0
  if (tid == 0) { sSx[0] = cx; sSy[0] = cy; sSz[0] = cz; }

  ull* myslots = slots + (size_t)beta * 2 * BPB;    // parity double-buffered

  for (int k = 0; k < NSEED - 1; ++k) {
    ull best = 0;
#pragma unroll
    for (int j = 0; j < PPT; ++j) {
      float dx = px[j] - cx, dy = py[j] - cy, dz = pz[j] - cz;
      // match numpy: round each square, sum as (d0+d1)+d2, no FMA contraction
      float d  = __fadd_rn(__fadd_rn(__fmul_rn(dx, dx), __fmul_rn(dy, dy)),
                           __fmul_rn(dz, dz));
      float nd = fminf(dist[j], d);
      dist[j]  = nd;
      int n    = blk * (TPB * PPT) + j * TPB + tid;
      ull p    = packdi(nd, n);
      best     = best > p ? best : p;
    }
    // wave-level argmax (butterfly)
#pragma unroll
    for (int o = 32; o > 0; o >>= 1) {
      ull q = __shfl_xor(best, o, 64);
      best  = best > q ? best : q;
    }
    if (lane == 0) sRed[k & 1][tid >> 6] = best;
    __syncthreads();   // barrier 1: sRed complete

    const ull gen = (ull)(k + 1);
    ull* arr = myslots + ((k + 1) & 1) * BPB;

    if (tid < 64) {   // ONLY wave 0 does the global exchange (anti-congestion)
      // cross-wave reduce via lanes 0..NW-1
      ull r = (lane < NW) ? sRed[k & 1][lane] : 0;
#pragma unroll
      for (int o = 8; o > 0; o >>= 1) {
        ull q = __shfl_xor(r, o, 64);
        r = r > q ? r : q;
      }
      if (lane == 0)
        __hip_atomic_store(&arr[blk], (gen << 48) | (r & PAYLOAD),
                           __ATOMIC_RELAXED, __HIP_MEMORY_SCOPE_AGENT);

      // poll: lanes 0..15 each watch one sibling slot in parallel
      for (;;) {
        ull v = 0;
        if (lane < BPB)
          v = __hip_atomic_load(&arr[lane], __ATOMIC_RELAXED,
                                __HIP_MEMORY_SCOPE_AGENT);
        int ok = (lane < BPB) ? (int)((v >> 48) == gen) : 1;
        if (__all(ok)) {
          ull w2 = (lane < BPB) ? (v & PAYLOAD) : 0;
#pragma unroll
          for (int o = 8; o > 0; o >>= 1) {
            ull q = __shfl_xor(w2, o, 64);
            w2 = w2 > q ? w2 : q;
          }
          if (lane == 0) sWin[k & 1] = w2;
          break;
        }
        __builtin_amdgcn_s_sleep(4);   // 256-cy backoff, keep line pressure low
      }
    }
    __syncthreads();   // barrier 2: sWin published

    ull win = sWin[k & 1];
    int widx = 0xFFFF ^ (int)(win & 0xFFFFull);
    // same-address broadcast load; pcs is read-only so L1 is safe
    cx = base[widx * 3 + 0];
    cy = base[widx * 3 + 1];
    cz = base[widx * 3 + 2];
    if (tid == 0) { sSx[k + 1] = cx; sSy[k + 1] = cy; sSz[k + 1] = cz; }
  }
  __syncthreads();   // sS[] complete before density phase

  // ---- density phase: points already in registers, seeds in LDS ----
  float* dden = den + beta * NSEED;
  for (int s = 0; s < NSEED; ++s) {
    float sx = sSx[s], sy = sSy[s], sz = sSz[s];
    float a = 0.f;
#pragma unroll
    for (int j = 0; j < PPT; ++j) {
      float dx = px[j] - sx, dy = py[j] - sy, dz = pz[j] - sz;
      float d  = dx * dx + dy * dy + dz * dz;
      a += fmaxf(R2 - d, 0.f);
    }
#pragma unroll
    for (int o = 32; o > 0; o >>= 1) a += __shfl_xor(a, o, 64);
    if (lane == 0) atomicAdd(&dden[s], a);
  }
}

__global__ void var_kernel(const float* __restrict__ den, float* __restrict__ out) {
  int l = threadIdx.x;
  float v = 0.f;
  if (l < NB) {
    float m = 0.f;
    for (int s = 0; s < NSEED; ++s) m += den[l * NSEED + s];
    m /= (float)NSEED;
    float q = 0.f;
    for (int s = 0; s < NSEED; ++s) { float d = den[l * NSEED + s] - m; q += d * d; }
    v = q / (float)(NSEED - 1);   // ddof=1
  }
  for (int o = 32; o > 0; o >>= 1) v += __shfl_xor(v, o, 64);
  if (l == 0) out[0] = v / (float)NB;
}

extern "C" void kernel_launch(void* const* d_in, const int* in_sizes, int n_in,
                              void* d_out, int out_size, void* d_ws, size_t ws_size,
                              hipStream_t stream) {
  const float* pcs = (const float*)d_in[0];
  float* out  = (float*)d_out;
  float* den  = (float*)d_ws;                       // 16*40*4   = 2560 B
  ull*   slots = (ull*)((char*)d_ws + 2560);        // 16*2*16*8 = 4096 B
  // slots need no init: poisoned 0xAA.. gives gen tag 0xAAAA, never in 1..39

  hipMemsetAsync(den, 0, NB * NSEED * sizeof(float), stream);

  void* args[3];
  args[0] = (void*)&pcs;
  args[1] = (void*)&slots;
  args[2] = (void*)&den;
  hipLaunchCooperativeKernel(reinterpret_cast<void*>(fps_den_kernel),
                             dim3(NB * BPB), dim3(TPB), args, 0, stream);

  hipLaunchKernelGGL(var_kernel, dim3(1), dim3(64), 0, stream, den, out);
}

// Round 5
// 284.781 us; speedup vs baseline: 1.3680x; 1.0068x over previous
//
#include <hip/hip_runtime.h>

typedef unsigned long long ull;

#define NB    16      // batches
#define NPTS  65536   // points per batch
#define NSEED 40      // seeds
#define BPB   16      // blocks per batch
#define TPB   1024    // threads per block (16 waves)
#define NW    (TPB/64)
#define PPT   4       // points per thread = NPTS/(BPB*TPB)
#define R2    0.0025f // RADIUS^2
#define PAYLOAD 0xFFFFFFFFFFFFull
#define LSTRIDE 8     // ulls per slot (64 B): one slot per cache line

// pack (value, index): unsigned max == (max value, then smallest index)
__device__ __forceinline__ ull packdi(float v, int idx) {
  return ((ull)__float_as_uint(v) << 16) | (ull)((unsigned)(idx ^ 0xFFFF) & 0xFFFFu);
}

__global__ __launch_bounds__(TPB, 4) void fps_den_kernel(
    const float* __restrict__ pcs, ull* __restrict__ slots, float* __restrict__ den)
{
  const int beta = blockIdx.x >> 4;   // batch
  const int blk  = blockIdx.x & 15;   // block within batch
  const int tid  = threadIdx.x;
  const int lane = tid & 63;
  const float* __restrict__ base = pcs + (size_t)beta * (NPTS * 3);

  __shared__ ull   sRed[2][NW];   // parity double-buffered wave maxima
  __shared__ ull   sWin[2];       // parity double-buffered round winner
  __shared__ float sSx[NSEED], sSy[NSEED], sSz[NSEED];

  // register-resident points + running min-distance
  float px[PPT], py[PPT], pz[PPT], dist[PPT];
#pragma unroll
  for (int j = 0; j < PPT; ++j) {
    int n = blk * (TPB * PPT) + j * TPB + tid;
    px[j] = base[n * 3 + 0];
    py[j] = base[n * 3 + 1];
    pz[j] = base[n * 3 + 2];
    dist[j] = 1e10f;
  }

  float cx = base[0], cy = base[1], cz = base[2];   // seed 0 = point 0
  if (tid == 0) { sSx[0] = cx; sSy[0] = cy; sSz[0] = cz; }

  // one 64-B line per slot: [beta][parity][blk] — pollers never queue behind
  // each other on a shared line, so the critical store lands immediately
  ull* myslots = slots + (size_t)beta * 2 * BPB * LSTRIDE;

  for (int k = 0; k < NSEED - 1; ++k) {
    ull best = 0;
#pragma unroll
    for (int j = 0; j < PPT; ++j) {
      float dx = px[j] - cx, dy = py[j] - cy, dz = pz[j] - cz;
      // match numpy: round each square, sum as (d0+d1)+d2, no FMA contraction
      float d  = __fadd_rn(__fadd_rn(__fmul_rn(dx, dx), __fmul_rn(dy, dy)),
                           __fmul_rn(dz, dz));
      float nd = fminf(dist[j], d);
      dist[j]  = nd;
      int n    = blk * (TPB * PPT) + j * TPB + tid;
      ull p    = packdi(nd, n);
      best     = best > p ? best : p;
    }
    // wave-level argmax (butterfly)
#pragma unroll
    for (int o = 32; o > 0; o >>= 1) {
      ull q = __shfl_xor(best, o, 64);
      best  = best > q ? best : q;
    }
    if (lane == 0) sRed[k & 1][tid >> 6] = best;
    __syncthreads();   // barrier 1: sRed complete

    const ull gen = (ull)(k + 1);
    ull* arr = myslots + (size_t)((k + 1) & 1) * BPB * LSTRIDE;

    if (tid < 64) {   // ONLY wave 0 does the global exchange
      ull r = (lane < NW) ? sRed[k & 1][lane] : 0;
#pragma unroll
      for (int o = 8; o > 0; o >>= 1) {
        ull q = __shfl_xor(r, o, 64);
        r = r > q ? r : q;
      }
      if (lane == 0)
        __hip_atomic_store(&arr[blk * LSTRIDE], (gen << 48) | (r & PAYLOAD),
                           __ATOMIC_RELAXED, __HIP_MEMORY_SCOPE_AGENT);

      // poll: lane i watches slot-line i (16 parallel single-line transactions)
      for (;;) {
        ull v = 0;
        if (lane < BPB)
          v = __hip_atomic_load(&arr[lane * LSTRIDE], __ATOMIC_RELAXED,
                                __HIP_MEMORY_SCOPE_AGENT);
        int ok = (lane < BPB) ? (int)((v >> 48) == gen) : 1;
        if (__all(ok)) {
          ull w2 = (lane < BPB) ? (v & PAYLOAD) : 0;
#pragma unroll
          for (int o = 8; o > 0; o >>= 1) {
            ull q = __shfl_xor(w2, o, 64);
            w2 = w2 > q ? w2 : q;
          }
          if (lane == 0) sWin[k & 1] = w2;
          break;
        }
        __builtin_amdgcn_s_sleep(8);   // ~512 cy backoff: keep line rate low
      }
    }
    __syncthreads();   // barrier 2: sWin published

    ull win = sWin[k & 1];
    int widx = 0xFFFF ^ (int)(win & 0xFFFFull);
    // same-address broadcast load; pcs is read-only so L1 is safe
    cx = base[widx * 3 + 0];
    cy = base[widx * 3 + 1];
    cz = base[widx * 3 + 2];
    if (tid == 0) { sSx[k + 1] = cx; sSy[k + 1] = cy; sSz[k + 1] = cz; }
  }
  __syncthreads();   // sS[] complete before density phase

  // ---- density phase: points already in registers, seeds in LDS ----
  float* dden = den + beta * NSEED;
  for (int s = 0; s < NSEED; ++s) {
    float sx = sSx[s], sy = sSy[s], sz = sSz[s];
    float a = 0.f;
#pragma unroll
    for (int j = 0; j < PPT; ++j) {
      float dx = px[j] - sx, dy = py[j] - sy, dz = pz[j] - sz;
      float d  = dx * dx + dy * dy + dz * dz;
      a += fmaxf(R2 - d, 0.f);
    }
#pragma unroll
    for (int o = 32; o > 0; o >>= 1) a += __shfl_xor(a, o, 64);
    if (lane == 0) atomicAdd(&dden[s], a);
  }
}

__global__ void var_kernel(const float* __restrict__ den, float* __restrict__ out) {
  int l = threadIdx.x;
  float v = 0.f;
  if (l < NB) {
    float m = 0.f;
    for (int s = 0; s < NSEED; ++s) m += den[l * NSEED + s];
    m /= (float)NSEED;
    float q = 0.f;
    for (int s = 0; s < NSEED; ++s) { float d = den[l * NSEED + s] - m; q += d * d; }
    v = q / (float)(NSEED - 1);   // ddof=1
  }
  for (int o = 32; o > 0; o >>= 1) v += __shfl_xor(v, o, 64);
  if (l == 0) out[0] = v / (float)NB;
}

extern "C" void kernel_launch(void* const* d_in, const int* in_sizes, int n_in,
                              void* d_out, int out_size, void* d_ws, size_t ws_size,
                              hipStream_t stream) {
  const float* pcs = (const float*)d_in[0];
  float* out  = (float*)d_out;
  float* den  = (float*)d_ws;                       // 16*40*4 = 2560 B
  ull*   slots = (ull*)((char*)d_ws + 4096);        // 16*2*16 lines * 64 B = 32 KB
  // slots need no init: poisoned 0xAA.. gives gen tag 0xAAAA, never in 1..39

  hipMemsetAsync(den, 0, NB * NSEED * sizeof(float), stream);

  // Regular launch: 256 blocks, 28 VGPR / 1 KB LDS -> 2 blocks/CU capacity,
  // grid (256) <= capacity (512) on 256 CUs => all blocks resident; algorithm
  // is dispatch-order-free (symmetric all-to-all, gen-tagged slots).
  fps_den_kernel<<<dim3(NB * BPB), dim3(TPB), 0, stream>>>(pcs, slots, den);
  var_kernel<<<dim3(1), dim3(64), 0, stream>>>(den, out);
}

// Round 6
// 206.913 us; speedup vs baseline: 1.8828x; 1.3763x over previous
//
#include <hip/hip_runtime.h>

typedef unsigned long long ull;

#define NB    16      // batches
#define NPTS  65536   // points per batch
#define NSEED 40      // seeds
#define BPB   16      // blocks per batch
#define TPB   1024    // threads per block (16 waves)
#define NW    16      // waves per block
#define PPT   4       // points per thread
#define R2    0.0025f // RADIUS^2
#define PAYLOAD 0xFFFFFFFFFFFFull

// pack (value, index): unsigned max == (max value, then smallest index)
__device__ __forceinline__ ull packdi(float v, int idx) {
  return ((ull)__float_as_uint(v) << 16) | (ull)((unsigned)(idx ^ 0xFFFF) & 0xFFFFu);
}

__global__ __launch_bounds__(TPB, 4) void fps_den_kernel(
    const float* __restrict__ pcs, ull* __restrict__ slots, float* __restrict__ pden)
{
  const int beta = blockIdx.x >> 4;   // batch
  const int blk  = blockIdx.x & 15;   // block within batch
  const int tid  = threadIdx.x;
  const int lane = tid & 63;
  const int wav  = tid >> 6;
  const float* __restrict__ base = pcs + (size_t)beta * (NPTS * 3);

  __shared__ ull   sRedP[2][NW];                    // parity-buffered wave winners
  __shared__ float sRedX[2][NW], sRedY[2][NW], sRedZ[2][NW];
  __shared__ float sWx[2], sWy[2], sWz[2];          // parity-buffered round winner
  __shared__ float sSx[NSEED], sSy[NSEED], sSz[NSEED];
  __shared__ float sDen[NW][NSEED];

  // register-resident points + running min-distance
  float px[PPT], py[PPT], pz[PPT], dist[PPT];
#pragma unroll
  for (int j = 0; j < PPT; ++j) {
    int n = blk * (TPB * PPT) + j * TPB + tid;
    px[j] = base[n * 3 + 0];
    py[j] = base[n * 3 + 1];
    pz[j] = base[n * 3 + 2];
    dist[j] = 1e10f;
  }

  float cx = base[0], cy = base[1], cz = base[2];   // seed 0 = point 0
  if (tid == 0) { sSx[0] = cx; sSy[0] = cy; sSz[0] = cz; }

  // record layout: [beta][parity][blk][word], word w = (gen<<48) | payload_w
  //   w0: dist/idx packed   w1: x bits   w2: y bits   w3: z bits
  // each word self-tagged with gen -> relaxed stores in any order are safe
  ull* myslots = slots + (size_t)beta * (2 * BPB * 4);

  for (int k = 0; k < NSEED - 1; ++k) {
    // thread-local best (payload order == (dist, then smallest idx))
    ull bestp = 0; float bx = 0.f, by = 0.f, bz = 0.f;
#pragma unroll
    for (int j = 0; j < PPT; ++j) {
      float dx = px[j] - cx, dy = py[j] - cy, dz = pz[j] - cz;
      // match numpy: round each square, sum as (d0+d1)+d2, no FMA contraction
      float d  = __fadd_rn(__fadd_rn(__fmul_rn(dx, dx), __fmul_rn(dy, dy)),
                           __fmul_rn(dz, dz));
      float nd = fminf(dist[j], d);
      dist[j]  = nd;
      int n    = blk * (TPB * PPT) + j * TPB + tid;
      ull p    = packdi(nd, n);
      if (p > bestp) { bestp = p; bx = px[j]; by = py[j]; bz = pz[j]; }
    }
    // wave argmax butterfly, carrying coords with the winner
#pragma unroll
    for (int o = 32; o > 0; o >>= 1) {
      ull   q  = __shfl_xor(bestp, o, 64);
      float qx = __shfl_xor(bx, o, 64);
      float qy = __shfl_xor(by, o, 64);
      float qz = __shfl_xor(bz, o, 64);
      if (q > bestp) { bestp = q; bx = qx; by = qy; bz = qz; }
    }
    if (lane == 0) {
      sRedP[k & 1][wav] = bestp;
      sRedX[k & 1][wav] = bx; sRedY[k & 1][wav] = by; sRedZ[k & 1][wav] = bz;
    }
    __syncthreads();   // barrier 1: sRed complete

    const ull gen = (ull)(k + 1);
    const ull g48 = gen << 48;
    ull* arr = myslots + (size_t)((k + 1) & 1) * (BPB * 4);

    if (wav == 0) {    // wave 0 does the entire global exchange
      // cross-wave argmax (lanes 0..15), carrying coords
      ull   rp = (lane < NW) ? sRedP[k & 1][lane] : 0;
      float rx = (lane < NW) ? sRedX[k & 1][lane] : 0.f;
      float ry = (lane < NW) ? sRedY[k & 1][lane] : 0.f;
      float rz = (lane < NW) ? sRedZ[k & 1][lane] : 0.f;
#pragma unroll
      for (int o = 8; o > 0; o >>= 1) {
        ull   q  = __shfl_xor(rp, o, 64);
        float qx = __shfl_xor(rx, o, 64);
        float qy = __shfl_xor(ry, o, 64);
        float qz = __shfl_xor(rz, o, 64);
        if (q > rp) { rp = q; rx = qx; ry = qy; rz = qz; }
      }
      // publish 32-B record via lanes 0..3 in ONE coalesced store instruction
      ull rec = g48 | (rp & PAYLOAD);
      if (lane == 1) rec = g48 | (ull)__float_as_uint(rx);
      if (lane == 2) rec = g48 | (ull)__float_as_uint(ry);
      if (lane == 3) rec = g48 | (ull)__float_as_uint(rz);
      if (lane < 4)
        __hip_atomic_store(&arr[blk * 4 + lane], rec,
                           __ATOMIC_RELAXED, __HIP_MEMORY_SCOPE_AGENT);

      // poll: 16 slots x 4 words = 64 words -> lane i watches word i.
      // whole exchange state arrives in ONE wave load per iteration.
      for (;;) {
        ull v = __hip_atomic_load(&arr[lane], __ATOMIC_RELAXED,
                                  __HIP_MEMORY_SCOPE_AGENT);
        if (__all((int)((v >> 48) == gen))) {
          ull pl = ((lane & 3) == 0) ? (v & PAYLOAD) : 0;
          ull m = pl;
#pragma unroll
          for (int o = 32; o > 0; o >>= 1) {
            ull q = __shfl_xor(m, o, 64);
            m = m > q ? m : q;
          }
          int has = (pl == m) && ((lane & 3) == 0);
          ull bal = __ballot(has);
          int src = __ffsll((long long)bal) - 1;   // winner's word-0 lane
          float f  = __uint_as_float((unsigned)(v & 0xFFFFFFFFull));
          float wx = __shfl(f, src + 1, 64);
          float wy = __shfl(f, src + 2, 64);
          float wz = __shfl(f, src + 3, 64);
          if (lane == 0) {
            sWx[k & 1] = wx; sWy[k & 1] = wy; sWz[k & 1] = wz;
            sSx[k + 1] = wx; sSy[k + 1] = wy; sSz[k + 1] = wz;
          }
          break;
        }
      }
    }
    __syncthreads();   // barrier 2: winner published
    cx = sWx[k & 1]; cy = sWy[k & 1]; cz = sWz[k & 1];
  }
  __syncthreads();   // sS[] complete before density phase

  // ---- density phase: points in registers, seeds in LDS ----
  for (int s = 0; s < NSEED; ++s) {
    float sx = sSx[s], sy = sSy[s], sz = sSz[s];
    float a = 0.f;
#pragma unroll
    for (int j = 0; j < PPT; ++j) {
      float dx = px[j] - sx, dy = py[j] - sy, dz = pz[j] - sz;
      float d  = dx * dx + dy * dy + dz * dz;
      a += fmaxf(R2 - d, 0.f);
    }
#pragma unroll
    for (int o = 32; o > 0; o >>= 1) a += __shfl_xor(a, o, 64);
    if (lane == 0) sDen[wav][s] = a;
  }
  __syncthreads();
  if (tid < NSEED) {   // per-block density partial, plain stores (no memset/atomics)
    float t = 0.f;
#pragma unroll
    for (int w = 0; w < NW; ++w) t += sDen[w][tid];
    pden[((size_t)beta * BPB + blk) * NSEED + tid] = t;
  }
}

__global__ void var_kernel(const float* __restrict__ pden, float* __restrict__ out) {
  __shared__ float sD[NB][NSEED];
  __shared__ float sV[NB];
  int t = threadIdx.x;
  if (t < NB * NSEED) {
    int beta = t / NSEED, s = t - beta * NSEED;
    float a = 0.f;
#pragma unroll
    for (int b = 0; b < BPB; ++b) a += pden[((size_t)beta * BPB + b) * NSEED + s];
    sD[beta][s] = a;
  }
  __syncthreads();
  if (t < NB) {
    float m = 0.f;
    for (int s = 0; s < NSEED; ++s) m += sD[t][s];
    m /= (float)NSEED;
    float q = 0.f;
    for (int s = 0; s < NSEED; ++s) { float d = sD[t][s] - m; q += d * d; }
    sV[t] = q / (float)(NSEED - 1);   // ddof=1
  }
  __syncthreads();
  if (t == 0) {
    float v = 0.f;
    for (int i = 0; i < NB; ++i) v += sV[i];
    out[0] = v / (float)NB;
  }
}

extern "C" void kernel_launch(void* const* d_in, const int* in_sizes, int n_in,
                              void* d_out, int out_size, void* d_ws, size_t ws_size,
                              hipStream_t stream) {
  const float* pcs = (const float*)d_in[0];
  float* out  = (float*)d_out;
  float* pden = (float*)d_ws;                       // 16*16*40*4 = 40960 B
  ull*   slots = (ull*)((char*)d_ws + 40960);       // 16*2*16*4*8 = 16384 B
  // slots need no init: poisoned 0xAA.. gives gen tag 0xAAAA, never in 1..39
  // pden needs no init: every entry written unconditionally each launch

  // Regular launch: 256 blocks of 16 waves; even worst-case packing (2
  // blocks/CU on 128 CUs) keeps ALL blocks resident -> spin loop is live.
  fps_den_kernel<<<dim3(NB * BPB), dim3(TPB), 0, stream>>>(pcs, slots, pden);
  var_kernel<<<dim3(1), dim3(TPB), 0, stream>>>(pden, out);
}

// Round 7
// 206.710 us; speedup vs baseline: 1.8846x; 1.0010x over previous
//
#include <hip/hip_runtime.h>

typedef unsigned long long ull;

#define NB    16      // batches
#define NPTS  65536   // points per batch
#define NSEED 40      // seeds
#define BPB   16      // blocks per batch
#define TPB   1024    // threads per block (16 waves)
#define NW    16      // waves per block
#define PPT   4       // points per thread
#define R2    0.0025f // RADIUS^2
#define PAYLOAD 0xFFFFFFFFFFFFull
#define POLLW2 8      // second (phase-offset) polling wave

// pack (value, index): unsigned max == (max value, then smallest index)
__device__ __forceinline__ ull packdi(float v, int idx) {
  return ((ull)__float_as_uint(v) << 16) | (ull)((unsigned)(idx ^ 0xFFFF) & 0xFFFFu);
}

__global__ __launch_bounds__(TPB, 4) void fps_den_kernel(
    const float* __restrict__ pcs, ull* __restrict__ slots, float* __restrict__ pden)
{
  const int beta = blockIdx.x >> 4;   // batch
  const int blk  = blockIdx.x & 15;   // block within batch
  const int tid  = threadIdx.x;
  const int lane = tid & 63;
  const int wav  = tid >> 6;
  const float* __restrict__ base = pcs + (size_t)beta * (NPTS * 3);

  __shared__ ull   sRedP[2][NW];                    // parity-buffered wave winners
  __shared__ float sRedX[2][NW], sRedY[2][NW], sRedZ[2][NW];
  __shared__ float sWx[2], sWy[2], sWz[2];          // parity-buffered round winner
  __shared__ float sDen[NW][NSEED];                 // per-wave density partials

  // register-resident points + running min-distance
  float px[PPT], py[PPT], pz[PPT], dist[PPT];
#pragma unroll
  for (int j = 0; j < PPT; ++j) {
    int n = blk * (TPB * PPT) + j * TPB + tid;
    px[j] = base[n * 3 + 0];
    py[j] = base[n * 3 + 1];
    pz[j] = base[n * 3 + 2];
    dist[j] = 1e10f;
  }

  float cx = base[0], cy = base[1], cz = base[2];   // seed 0 = point 0

  // record layout: [beta][parity][blk][word], word w = (gen<<48) | payload_w
  //   w0: dist/idx packed   w1: x bits   w2: y bits   w3: z bits
  ull* myslots = slots + (size_t)beta * (2 * BPB * 4);

  for (int k = 0; k < NSEED - 1; ++k) {
    // ---- min-update + local argmax for next seed ----
    ull bestp = 0; float bx = 0.f, by = 0.f, bz = 0.f;
#pragma unroll
    for (int j = 0; j < PPT; ++j) {
      float dx = px[j] - cx, dy = py[j] - cy, dz = pz[j] - cz;
      // match numpy: round each square, sum as (d0+d1)+d2, no FMA contraction
      float d  = __fadd_rn(__fadd_rn(__fmul_rn(dx, dx), __fmul_rn(dy, dy)),
                           __fmul_rn(dz, dz));
      float nd = fminf(dist[j], d);
      dist[j]  = nd;
      int n    = blk * (TPB * PPT) + j * TPB + tid;
      ull p    = packdi(nd, n);
      if (p > bestp) { bestp = p; bx = px[j]; by = py[j]; bz = pz[j]; }
    }
#pragma unroll
    for (int o = 32; o > 0; o >>= 1) {
      ull   q  = __shfl_xor(bestp, o, 64);
      float qx = __shfl_xor(bx, o, 64);
      float qy = __shfl_xor(by, o, 64);
      float qz = __shfl_xor(bz, o, 64);
      if (q > bestp) { bestp = q; bx = qx; by = qy; bz = qz; }
    }
    if (lane == 0) {
      sRedP[k & 1][wav] = bestp;
      sRedX[k & 1][wav] = bx; sRedY[k & 1][wav] = by; sRedZ[k & 1][wav] = bz;
    }
    __syncthreads();   // barrier 1

    const ull gen = (ull)(k + 1);
    const ull g48 = gen << 48;
    ull* arr = myslots + (size_t)((k + 1) & 1) * (BPB * 4);

    // ---- density for CURRENT seed c_k, overlapped with the exchange ----
    // (wave 0 defers its density to after its store; waves 1..15 do it now)
    float da = 0.f;
    if (wav != 0) {
#pragma unroll
      for (int j = 0; j < PPT; ++j) {
        float dx = px[j] - cx, dy = py[j] - cy, dz = pz[j] - cz;
        float d  = dx * dx + dy * dy + dz * dz;
        da += fmaxf(R2 - d, 0.f);
      }
#pragma unroll
      for (int o = 32; o > 0; o >>= 1) da += __shfl_xor(da, o, 64);
      if (lane == 0) sDen[wav][k] = da;
    }

    if (wav == 0 || wav == POLLW2) {
      if (wav == 0) {
        // cross-wave argmax (lanes 0..15), carrying coords
        ull   rp = (lane < NW) ? sRedP[k & 1][lane] : 0;
        float rx = (lane < NW) ? sRedX[k & 1][lane] : 0.f;
        float ry = (lane < NW) ? sRedY[k & 1][lane] : 0.f;
        float rz = (lane < NW) ? sRedZ[k & 1][lane] : 0.f;
#pragma unroll
        for (int o = 8; o > 0; o >>= 1) {
          ull   q  = __shfl_xor(rp, o, 64);
          float qx = __shfl_xor(rx, o, 64);
          float qy = __shfl_xor(ry, o, 64);
          float qz = __shfl_xor(rz, o, 64);
          if (q > rp) { rp = q; rx = qx; ry = qy; rz = qz; }
        }
        ull rec = g48 | (rp & PAYLOAD);
        if (lane == 1) rec = g48 | (ull)__float_as_uint(rx);
        if (lane == 2) rec = g48 | (ull)__float_as_uint(ry);
        if (lane == 3) rec = g48 | (ull)__float_as_uint(rz);
        if (lane < 4)   // RMW: commits promptly at the coherence point
          (void)__hip_atomic_exchange(&arr[blk * 4 + lane], rec,
                                      __ATOMIC_RELAXED, __HIP_MEMORY_SCOPE_AGENT);
        // wave 0's own density while the store flies
#pragma unroll
        for (int j = 0; j < PPT; ++j) {
          float dx = px[j] - cx, dy = py[j] - cy, dz = pz[j] - cz;
          float d  = dx * dx + dy * dy + dz * dz;
          da += fmaxf(R2 - d, 0.f);
        }
#pragma unroll
        for (int o = 32; o > 0; o >>= 1) da += __shfl_xor(da, o, 64);
        if (lane == 0) sDen[0][k] = da;
      }
      // poll: 16 slots x 4 words = 64 words -> lane i watches word i.
      // two waves at uncorrelated phases halve expected discovery lag.
      for (;;) {
        ull v = __hip_atomic_load(&arr[lane], __ATOMIC_RELAXED,
                                  __HIP_MEMORY_SCOPE_AGENT);
        if (__all((int)((v >> 48) == gen))) {
          ull pl = ((lane & 3) == 0) ? (v & PAYLOAD) : 0;
          ull m = pl;
#pragma unroll
          for (int o = 32; o > 0; o >>= 1) {
            ull q = __shfl_xor(m, o, 64);
            m = m > q ? m : q;
          }
          int has = (pl == m) && ((lane & 3) == 0);
          ull bal = __ballot(has);
          int src = __ffsll((long long)bal) - 1;   // winner's word-0 lane
          float f  = __uint_as_float((unsigned)(v & 0xFFFFFFFFull));
          float wx = __shfl(f, src + 1, 64);
          float wy = __shfl(f, src + 2, 64);
          float wz = __shfl(f, src + 3, 64);
          if (lane == 0) {   // both pollers may write: identical values, benign
            sWx[k & 1] = wx; sWy[k & 1] = wy; sWz[k & 1] = wz;
          }
          break;
        }
      }
    }
    __syncthreads();   // barrier 2: winner published
    cx = sWx[k & 1]; cy = sWy[k & 1]; cz = sWz[k & 1];
  }

  // ---- density for the last seed (c_39) ----
  {
    float a = 0.f;
#pragma unroll
    for (int j = 0; j < PPT; ++j) {
      float dx = px[j] - cx, dy = py[j] - cy, dz = pz[j] - cz;
      float d  = dx * dx + dy * dy + dz * dz;
      a += fmaxf(R2 - d, 0.f);
    }
#pragma unroll
    for (int o = 32; o > 0; o >>= 1) a += __shfl_xor(a, o, 64);
    if (lane == 0) sDen[wav][NSEED - 1] = a;
  }
  __syncthreads();

  if (tid < NSEED) {   // per-block density partial, plain stores
    float t = 0.f;
#pragma unroll
    for (int w = 0; w < NW; ++w) t += sDen[w][tid];
    pden[((size_t)beta * BPB + blk) * NSEED + tid] = t;
  }
}

__global__ void var_kernel(const float* __restrict__ pden, float* __restrict__ out) {
  __shared__ float sD[NB][NSEED];
  __shared__ float sV[NB];
  int t = threadIdx.x;
  if (t < NB * NSEED) {
    int beta = t / NSEED, s = t - beta * NSEED;
    float a = 0.f;
#pragma unroll
    for (int b = 0; b < BPB; ++b) a += pden[((size_t)beta * BPB + b) * NSEED + s];
    sD[beta][s] = a;
  }
  __syncthreads();
  if (t < NB) {
    float m = 0.f;
    for (int s = 0; s < NSEED; ++s) m += sD[t][s];
    m /= (float)NSEED;
    float q = 0.f;
    for (int s = 0; s < NSEED; ++s) { float d = sD[t][s] - m; q += d * d; }
    sV[t] = q / (float)(NSEED - 1);   // ddof=1
  }
  __syncthreads();
  if (t == 0) {
    float v = 0.f;
    for (int i = 0; i < NB; ++i) v += sV[i];
    out[0] = v / (float)NB;
  }
}

extern "C" void kernel_launch(void* const* d_in, const int* in_sizes, int n_in,
                              void* d_out, int out_size, void* d_ws, size_t ws_size,
                              hipStream_t stream) {
  const float* pcs = (const float*)d_in[0];
  float* out  = (float*)d_out;
  float* pden = (float*)d_ws;                       // 16*16*40*4 = 40960 B
  ull*   slots = (ull*)((char*)d_ws + 40960);       // 16*2*16*4*8 = 16384 B
  // slots need no init: poisoned 0xAA.. gives gen tag 0xAAAA, never in 1..39
  // pden needs no init: every entry written unconditionally each launch

  fps_den_kernel<<<dim3(NB * BPB), dim3(TPB), 0, stream>>>(pcs, slots, pden);
  var_kernel<<<dim3(1), dim3(TPB), 0, stream>>>(pden, out);
}